// Round 9
// baseline (24.073 us; speedup 1.0000x reference)
//
#include <hip/hip_runtime.h>
#include <math.h>

#define L 512
#define NTHREADS 256
#define TSPAN 8           // t's per wave (registers: acc[8] float4 + ps[8])
#define BLOCK_T 32        // 4 waves x TSPAN
#define ZWIN 9.0f         // dropped pdf mass <= exp(-40.5): < 1e-10 effect on output
#define NXCD 8

static constexpr float EPS = 1e-6f;
static constexpr float INV_SQRT_2PI = 0.39894228040143267794f;

__global__ __launch_bounds__(NTHREADS, 4) void ge_kernel(
    const float* __restrict__ text,  // [B, L, D]
    const int*   __restrict__ durs,  // [B, L]
    float*       __restrict__ out,   // [B, T, D]
    int B, int D, int T, int tilesPerB, int nwg)
{
    __shared__ float2 s_mi[L];   // (mean, 1/sigma); every wave writes all entries (identical values)

    const int tid  = threadIdx.x;
    const int lane = tid & 63;
    const int wid  = tid >> 6;

    // XCD-aware bijective swizzle (only when exact)
    const int orig = blockIdx.x;
    const int wg   = (nwg % NXCD == 0) ? (orig & (NXCD - 1)) * (nwg / NXCD) + (orig >> 3)
                                       : orig;
    const int b    = wg / tilesPerB;
    const int t0w  = (wg % tilesPerB) * BLOCK_T + wid * TSPAN;   // this wave's 8 t's

    // ---- wave-private full cumsum: lane owns rows 8*lane..8*lane+7 ----
    const int r0 = lane << 3;
    const int4* dp = (const int4*)(durs + (size_t)b * L + r0);
    const int4 da = dp[0];
    const int4 db = dp[1];
    int dv[8] = {da.x, da.y, da.z, da.w, db.x, db.y, db.z, db.w};
    int csum[8];
    {
        int run = 0;
        #pragma unroll
        for (int j = 0; j < 8; ++j) { run += dv[j]; csum[j] = run; }
        int v = run;
        #pragma unroll
        for (int off = 1; off < 64; off <<= 1) {
            int n = __shfl_up(v, off, 64);
            if (lane >= off) v += n;
        }
        const int excl = v - run;
        #pragma unroll
        for (int j = 0; j < 8; ++j) csum[j] += excl;   // inclusive cumsum
    }

    // ---- params to LDS + this wave's active band [myMin, myMax] (superset cover = exact) ----
    const float tlo = (float)t0w + 0.5f;
    const float thi = (float)t0w + (float)TSPAN - 0.5f;
    int myMin = L, myMax = -1;
    #pragma unroll
    for (int j = 0; j < 8; ++j) {
        const float d  = (float)dv[j];
        const float m  = (float)csum[j] + 0.5f * d;    // cumsum_incl + d/2
        const float sg = 0.5f * d + EPS;
        s_mi[r0 + j] = make_float2(m, 1.0f / sg);
        const float r = ZWIN * sg;
        if ((dv[j] >= 1) && (m + r >= tlo) && (m - r <= thi)) {
            myMin = min(myMin, r0 + j);
            myMax = max(myMax, r0 + j);
        }
    }
    #pragma unroll
    for (int off = 32; off > 0; off >>= 1) {
        myMin = min(myMin, __shfl_xor(myMin, off, 64));
        myMax = max(myMax, __shfl_xor(myMax, off, 64));
    }
    // this wave wrote every s_mi entry itself (other waves write identical values) -> wave fence only
    asm volatile("s_waitcnt lgkmcnt(0)" ::: "memory");
    __builtin_amdgcn_sched_barrier(0);

    // ---- rows-outer / t-inner: 1 text load + 1 LDS broadcast feed 32 FMAs ----
    float4 acc[TSPAN];
    float  ps[TSPAN];
    #pragma unroll
    for (int k = 0; k < TSPAN; ++k) { acc[k] = make_float4(0.f, 0.f, 0.f, 0.f); ps[k] = 0.f; }

    const float* tb  = text + (size_t)b * L * D + (lane << 2);
    const float  tf0 = (float)t0w + 0.5f;

    #pragma unroll 2
    for (int l = myMin; l <= myMax; ++l) {
        const float2 mi  = s_mi[l];                              // wave-uniform broadcast
        const float4 val = *(const float4*)(tb + (size_t)l * D); // one load per row
        const float  c   = mi.y * INV_SQRT_2PI;
        const float  z0  = (tf0 - mi.x) * mi.y;
        #pragma unroll
        for (int k = 0; k < TSPAN; ++k) {
            const float zk = fmaf((float)k, mi.y, z0);
            const float p  = __expf(-0.5f * zk * zk) * c;        // wave-uniform
            ps[k] += p;                                          // uniform -> no reduce needed
            acc[k].x += p * val.x;
            acc[k].y += p * val.y;
            acc[k].z += p * val.z;
            acc[k].w += p * val.w;
        }
    }

    // ---- normalize + store: wave writes 8 consecutive 1 KB rows ----
    float* ob = out + ((size_t)b * T + t0w) * D + (lane << 2);
    #pragma unroll
    for (int k = 0; k < TSPAN; ++k) {
        if (t0w + k < T) {
            const float rn = 1.0f / (ps[k] + EPS);
            *(float4*)(ob + (size_t)k * D) =
                make_float4(acc[k].x * rn, acc[k].y * rn, acc[k].z * rn, acc[k].w * rn);
        }
    }
}

extern "C" void kernel_launch(void* const* d_in, const int* in_sizes, int n_in,
                              void* d_out, int out_size, void* d_ws, size_t ws_size,
                              hipStream_t stream) {
    const float* text = (const float*)d_in[0];
    const int*   durs = (const int*)d_in[1];
    float*       out  = (float*)d_out;

    const int BL = in_sizes[1];        // B * L
    const int D  = in_sizes[0] / BL;   // 256
    const int B  = BL / L;             // 16
    const int T  = out_size / (B * D); // 2048
    const int tilesPerB = (T + BLOCK_T - 1) / BLOCK_T;
    const int nwg = B * tilesPerB;     // 1024 for the bench shape

    ge_kernel<<<dim3(nwg), dim3(NTHREADS), 0, stream>>>(
        text, durs, out, B, D, T, tilesPerB, nwg);
}

// Round 10
// 21.637 us; speedup vs baseline: 1.1126x; 1.1126x over previous
//
#include <hip/hip_runtime.h>
#include <math.h>

#define L 512
#define TILE_T 16
#define NTHREADS 256
#define ZWIN 9.0f        // dropped pdf mass <= exp(-40.5): < 1e-10 effect on output
#define NXCD 8
#define OCT 8

static constexpr float EPS = 1e-6f;
static constexpr float INV_SQRT_2PI = 0.39894228040143267794f;

// ---------------- K1: params + per-tile window table ----------------
// grid = B*OCT blocks. Each block: full scan for batch b; octant 'oct' fills
// its slice of the tile table. oct==0 also writes params float2[L].
__global__ __launch_bounds__(NTHREADS) void ge_params(
    const int* __restrict__ durs,     // [B, L]
    float2*    __restrict__ pw,       // [B, L] (mean, 1/sigma)
    int2*      __restrict__ tbl,      // [B, tilesPerB] (lmin, width)
    int tilesPerB)
{
    __shared__ float s_wtot[4];
    __shared__ int   s_mn[64], s_mx[64];

    const int tid  = threadIdx.x;
    const int lane = tid & 63;
    const int wid  = tid >> 6;
    const int b    = blockIdx.x >> 3;
    const int oct  = blockIdx.x & (OCT - 1);
    const int octTiles = (tilesPerB + OCT - 1) / OCT;
    const int jbase = oct * octTiles;

    for (int j = tid; j < octTiles; j += NTHREADS) { s_mn[j] = 0x7fffffff; s_mx[j] = -1; }

    // pair scan (2 rows per thread)
    const int l0 = 2 * tid;
    const float d0 = (float)durs[b * L + l0];
    const float d1 = (float)durs[b * L + l0 + 1];
    const float pairsum = d0 + d1;
    float v = pairsum;
    #pragma unroll
    for (int off = 1; off < 64; off <<= 1) {
        float n = __shfl_up(v, off, 64);
        if (lane >= off) v += n;
    }
    if (lane == 63) s_wtot[wid] = v;
    __syncthreads();
    float wpre = 0.f;
    for (int w = 0; w < wid; ++w) wpre += s_wtot[w];
    const float excl = wpre + v - pairsum;

    const float cum0 = excl + d0, cum1 = cum0 + d1;
    const float m0 = cum0 + 0.5f * d0, m1 = cum1 + 0.5f * d1;
    const float sg0 = 0.5f * d0 + EPS, sg1 = 0.5f * d1 + EPS;
    if (oct == 0) {
        pw[b * L + l0]     = make_float2(m0, 1.0f / sg0);
        pw[b * L + l0 + 1] = make_float2(m1, 1.0f / sg1);
    }

    // scatter each active row's tile coverage into this octant's table slice
    #pragma unroll
    for (int half = 0; half < 2; ++half) {
        const float d  = half ? d1 : d0;
        const float m  = half ? m1 : m0;
        const float sg = half ? sg1 : sg0;
        const int   l  = l0 + half;
        if (d >= 1.f) {
            const float r = ZWIN * sg;
            int jmin = (int)ceilf((m - r - ((float)TILE_T - 0.5f)) / (float)TILE_T);
            int jmax = (int)floorf((m + r - 0.5f) / (float)TILE_T);
            jmin = max(jmin, jbase);
            jmax = min(jmax, min(jbase + octTiles - 1, tilesPerB - 1));
            for (int j = jmin; j <= jmax; ++j) {
                atomicMin(&s_mn[j - jbase], l);
                atomicMax(&s_mx[j - jbase], l);
            }
        }
    }
    __syncthreads();
    for (int j = tid; j < octTiles; j += NTHREADS) {
        const int jj = jbase + j;
        if (jj < tilesPerB) {
            const int mn = s_mn[j], mx = s_mx[j];
            tbl[b * tilesPerB + jj] = make_int2((mx >= mn) ? mn : 0,
                                                (mx >= mn) ? (mx - mn + 1) : 0);
        }
    }
}

// ---------------- K2: lean consumer (no scan/ballot/barrier) ----------------
__global__ __launch_bounds__(NTHREADS, 8) void ge_main(
    const float*  __restrict__ text,  // [B, L, D]
    const float2* __restrict__ pw,    // [B, L]
    const int2*   __restrict__ tbl,   // [B, tilesPerB]
    float*        __restrict__ out,   // [B, T, D]
    int B, int D, int T, int tilesPerB, int nwg)
{
    __shared__ float4 s_p[4][64];     // per-wave probs: [item] -> (p_t0..p_t3)

    const int tid  = threadIdx.x;
    const int lane = tid & 63;
    const int wid  = tid >> 6;

    const int orig = blockIdx.x;
    const int wg   = (nwg % NXCD == 0) ? (orig & (NXCD - 1)) * (nwg / NXCD) + (orig >> 3)
                                       : orig;
    const int b    = wg / tilesPerB;
    const int tile = wg % tilesPerB;
    const int t0   = tile * TILE_T;

    const int2 wi  = tbl[b * tilesPerB + tile];   // uniform -> scalar load
    const int lmin = wi.x, nb = wi.y;

    const float tq = (float)(t0 + (wid << 2)) + 0.5f;
    float4 a0 = {0,0,0,0}, a1 = {0,0,0,0}, a2 = {0,0,0,0}, a3 = {0,0,0,0};
    float ps0 = 0.f, ps1 = 0.f, ps2 = 0.f, ps3 = 0.f;
    const float* tb = text + (size_t)b * L * D + (lane << 2);

    for (int base = 0; base < nb; base += 64) {
        const int cnt = min(64, nb - base);

        float4 pv = {0.f, 0.f, 0.f, 0.f};
        if (lane < cnt) {
            const float2 pm = pw[b * L + lmin + base + lane];   // coalesced 8B/lane
            const float F  = -0.5f * pm.y * pm.y;
            const float c  = pm.y * INV_SQRT_2PI;
            const float u0 = tq - pm.x;
            const float u1 = u0 + 1.f, u2 = u0 + 2.f, u3 = u0 + 3.f;
            pv.x = __expf(F * u0 * u0) * c;
            pv.y = __expf(F * u1 * u1) * c;
            pv.z = __expf(F * u2 * u2) * c;
            pv.w = __expf(F * u3 * u3) * c;
        }
        if (base > 0) {  // WAR fence: prior chunk's reads must drain before overwrite
            asm volatile("s_waitcnt lgkmcnt(0)" ::: "memory");
            __builtin_amdgcn_sched_barrier(0);
        }
        s_p[wid][lane] = pv;
        asm volatile("s_waitcnt lgkmcnt(0)" ::: "memory");      // wave-local RAW fence
        __builtin_amdgcn_sched_barrier(0);

        const float* tc = tb + (size_t)(lmin + base) * D;
        const int maxoff = (L - 1) - (lmin + base);
        const int niter = (cnt + 1) & ~1;                       // even; s_p zero-padded
        float4 v0 = *(const float4*)(tc + (size_t)min(0, maxoff) * D);
        float4 v1 = *(const float4*)(tc + (size_t)min(1, maxoff) * D);
        for (int i = 0; i < niter; i += 2) {
            const float4 w0 = v0, w1 = v1;
            v0 = *(const float4*)(tc + (size_t)min(i + 2, maxoff) * D);
            v1 = *(const float4*)(tc + (size_t)min(i + 3, maxoff) * D);
            const float4 q0 = s_p[wid][i];                      // wave-uniform broadcast
            const float4 q1 = s_p[wid][i + 1];
            ps0 += q0.x + q1.x; ps1 += q0.y + q1.y;
            ps2 += q0.z + q1.z; ps3 += q0.w + q1.w;
            a0.x += q0.x*w0.x + q1.x*w1.x; a0.y += q0.x*w0.y + q1.x*w1.y;
            a0.z += q0.x*w0.z + q1.x*w1.z; a0.w += q0.x*w0.w + q1.x*w1.w;
            a1.x += q0.y*w0.x + q1.y*w1.x; a1.y += q0.y*w0.y + q1.y*w1.y;
            a1.z += q0.y*w0.z + q1.y*w1.z; a1.w += q0.y*w0.w + q1.y*w1.w;
            a2.x += q0.z*w0.x + q1.z*w1.x; a2.y += q0.z*w0.y + q1.z*w1.y;
            a2.z += q0.z*w0.z + q1.z*w1.z; a2.w += q0.z*w0.w + q1.z*w1.w;
            a3.x += q0.w*w0.x + q1.w*w1.x; a3.y += q0.w*w0.y + q1.w*w1.y;
            a3.z += q0.w*w0.z + q1.w*w1.z; a3.w += q0.w*w0.w + q1.w*w1.w;
        }
    }

    const float rn0 = 1.0f / (ps0 + EPS);
    const float rn1 = 1.0f / (ps1 + EPS);
    const float rn2 = 1.0f / (ps2 + EPS);
    const float rn3 = 1.0f / (ps3 + EPS);

    const int ttq = t0 + (wid << 2);
    float* ob = out + ((size_t)b * T + ttq) * D + (lane << 2);
    if (ttq + 0 < T) *(float4*)(ob + 0*(size_t)D) = make_float4(a0.x*rn0, a0.y*rn0, a0.z*rn0, a0.w*rn0);
    if (ttq + 1 < T) *(float4*)(ob + 1*(size_t)D) = make_float4(a1.x*rn1, a1.y*rn1, a1.z*rn1, a1.w*rn1);
    if (ttq + 2 < T) *(float4*)(ob + 2*(size_t)D) = make_float4(a2.x*rn2, a2.y*rn2, a2.z*rn2, a2.w*rn2);
    if (ttq + 3 < T) *(float4*)(ob + 3*(size_t)D) = make_float4(a3.x*rn3, a3.y*rn3, a3.z*rn3, a3.w*rn3);
}

extern "C" void kernel_launch(void* const* d_in, const int* in_sizes, int n_in,
                              void* d_out, int out_size, void* d_ws, size_t ws_size,
                              hipStream_t stream) {
    const float* text = (const float*)d_in[0];
    const int*   durs = (const int*)d_in[1];
    float*       out  = (float*)d_out;

    const int BL = in_sizes[1];        // B * L
    const int D  = in_sizes[0] / BL;   // 256
    const int B  = BL / L;             // 16
    const int T  = out_size / (B * D); // 2048
    const int tilesPerB = (T + TILE_T - 1) / TILE_T;   // 128
    const int nwg = B * tilesPerB;     // 2048

    float2* pw  = (float2*)d_ws;
    int2*   tbl = (int2*)((char*)d_ws + (size_t)B * L * sizeof(float2));

    ge_params<<<dim3(B * OCT), dim3(NTHREADS), 0, stream>>>(durs, pw, tbl, tilesPerB);
    ge_main  <<<dim3(nwg),     dim3(NTHREADS), 0, stream>>>(text, pw, tbl, out,
                                                            B, D, T, tilesPerB, nwg);
}